// Round 1
// baseline (9372.735 us; speedup 1.0000x reference)
//
#include <hip/hip_runtime.h>

// LSTM T=512 B=256 NP=34 H=512 NT=16.
// 16 groups (16 batches) x 16 blocks (32 h-cols, all 4 gates), W slice in LDS.
// R4: barrier-free T-loop. Each lane polls the exact 2 u64s per h-slice that
// form its MFMA A-fragment (self-validating sentinel protocol, relaxed agent
// scope, unchanged semantics) -> no h LDS staging, no __syncthreads in loop.
// W rows reordered r = col*4 + gate so one wave owns all 4 gates of its 8
// cols; epilogue gathers i,f,g,o per cell with 3 quad-perm DPPs (lane q owns
// reg q -> 64 lanes x 2 cells, zero redundancy), c-state in registers,
// h packed with one shfl_xor(4). 4 MFMA accumulator chains halve dep latency.
#define TT 512
#define BT 256
#define NP 34
#define HH 512
#define SENT 0xAAAAAAAAu

typedef short bf16x8 __attribute__((ext_vector_type(8)));
typedef float f32x4 __attribute__((ext_vector_type(4)));

static __device__ __forceinline__ unsigned short f2bf(float x) {
  unsigned int u = __float_as_uint(x);
  return (unsigned short)((u + 0x7fffu + ((u >> 16) & 1u)) >> 16);
}

template <int CTRL>
static __device__ __forceinline__ float dppq(float x) {
  return __int_as_float(
      __builtin_amdgcn_mov_dpp(__float_as_int(x), CTRL, 0xF, 0xF, true));
}

static __device__ __forceinline__ float rcpf(float x) {
  return __builtin_amdgcn_rcpf(x);
}

// LDS (147456 B dynamic): W slice bf16 [128 rows][576], 16B-chunk swizzle
// phys_chunk = c ^ (r&7). Row r = j*4 + q  (j = col in [0,32), q = gate ifgo).
__global__ void __launch_bounds__(256, 1) lstm_coop(
    const float* __restrict__ Whh, const float* __restrict__ Wih,
    const float* __restrict__ bih, const float* __restrict__ bhh,
    const unsigned short* __restrict__ Ax,  // [T][256][64] bf16: [points(34),0..]
    unsigned short* hs)                     // [T][256][512] bf16, pre-set SENT
{
  extern __shared__ char smem[];
  unsigned short* Wl = (unsigned short*)smem;

  const int tid = threadIdx.x;
  const int g = blockIdx.x & 15;   // group
  const int n = blockIdx.x >> 4;   // h-col slice [n*32, n*32+32)
  const int bbase = g * 16;

  // ---- init resident W slice (swizzled, reordered rows) ----
  for (int idx = tid; idx < 128 * 576; idx += 256) {
    int r = idx / 576, k = idx - r * 576;
    int grow = (r & 3) * 512 + n * 32 + (r >> 2);  // gate q=r&3, col j=r>>2
    float v = 0.f;
    if (k < 512) v = Whh[(size_t)grow * 512 + k];
    else if (k < 546) v = Wih[grow * 34 + (k - 512)];
    int c = k >> 3, within = k & 7;
    Wl[r * 576 + ((c ^ (r & 7)) << 3) + within] = f2bf(v);
  }
  __syncthreads();  // only barrier in the kernel: Wl is read-only afterwards

  const int lane = tid & 63;
  const int w = tid >> 6;        // wave: owns cols [8w, 8w+8) of this slice
  const int m = lane & 15;       // A row (batch) / B tile-row
  const int ko = lane >> 4;      // k-subgroup
  const int r0 = 32 * w + m;
  const int q = m & 3;           // gate owned by this lane (B-tile row -> q)
  const int jj = m >> 2;         // col-in-wave quad group
  const int j0 = 8 * w + jj;     // acc0 col (block-local)
  const int j1 = j0 + 4;         // acc1 col
  const int mx = m & 7;

  // biases for all 4 gates at cols j0, j1 (needed after quad gather)
  float bi0[4], bi1[4];
#pragma unroll
  for (int gg = 0; gg < 4; ++gg) {
    int gr0 = gg * 512 + n * 32 + j0;
    int gr1 = gg * 512 + n * 32 + j1;
    bi0[gg] = bih[gr0] + bhh[gr0];
    bi1[gg] = bih[gr1] + bhh[gr1];
  }

  // hoisted x-slice W fragments (constant over t)
  bf16x8 bx0a = *(const bf16x8*)&Wl[r0 * 576 + (((64 + ko) ^ mx) << 3)];
  bf16x8 bx1a = *(const bf16x8*)&Wl[(r0 + 16) * 576 + (((64 + ko) ^ mx) << 3)];
  bf16x8 bx0b = *(const bf16x8*)&Wl[r0 * 576 + (((68 + ko) ^ mx) << 3)];
  bf16x8 bx1b = *(const bf16x8*)&Wl[(r0 + 16) * 576 + (((68 + ko) ^ mx) << 3)];

  const bool q0 = (q == 0), q1 = (q == 1), q2 = (q == 2);
  float cc0 = 0.f, cc1 = 0.f;  // cell state for (batch 4ko+q, cols j0/j1)

  for (int t = 0; t < TT; ++t) {
    // x fragments for this step (independent of h; latency hides under poll)
    const unsigned short* xbase = Ax + ((size_t)t * BT + bbase + m) * 64;
    bf16x8 xv0 = *(const bf16x8*)(xbase + (ko << 3));
    bf16x8 xv1 = *(const bf16x8*)(xbase + 32 + (ko << 3));

    // ---- Phase A: poll own A-fragment u64s, mask-driven, pipelined ----
    unsigned long long u0[16], u1[16];
    if (t > 0) {
      const unsigned long long* pb =
          (const unsigned long long*)hs +
          ((size_t)(t - 1) * BT + bbase + m) * 128 + 2 * ko;
      unsigned int vm = 0;
      int guard = 0;
      while (!__all((int)(vm == 0xffffu))) {
#pragma unroll
        for (int s = 0; s < 16; ++s) {  // issue (no checks between loads)
          if (!((vm >> s) & 1u)) {
            u0[s] = __hip_atomic_load(pb + 8 * s, __ATOMIC_RELAXED,
                                      __HIP_MEMORY_SCOPE_AGENT);
            u1[s] = __hip_atomic_load(pb + 8 * s + 1, __ATOMIC_RELAXED,
                                      __HIP_MEMORY_SCOPE_AGENT);
          }
        }
#pragma unroll
        for (int s = 0; s < 16; ++s) {  // check
          if (!((vm >> s) & 1u)) {
            unsigned long long a = u0[s], b = u1[s];
            bool ok = ((unsigned)a != SENT) && ((unsigned)(a >> 32) != SENT) &&
                      ((unsigned)b != SENT) && ((unsigned)(b >> 32) != SENT);
            vm |= ok ? (1u << s) : 0u;
          }
        }
        if (__all((int)(vm == 0xffffu))) break;
        if (++guard > (1 << 20)) break;  // deadlock guard
        __builtin_amdgcn_s_sleep(1);
      }
    }

    // ---- Phase B: gates GEMM, 4 accumulator chains ----
    f32x4 a0a = {0.f, 0.f, 0.f, 0.f}, a0b = {0.f, 0.f, 0.f, 0.f};
    f32x4 a1a = {0.f, 0.f, 0.f, 0.f}, a1b = {0.f, 0.f, 0.f, 0.f};
    a0a = __builtin_amdgcn_mfma_f32_16x16x32_bf16(xv0, bx0a, a0a, 0, 0, 0);
    a1a = __builtin_amdgcn_mfma_f32_16x16x32_bf16(xv0, bx1a, a1a, 0, 0, 0);
    a0b = __builtin_amdgcn_mfma_f32_16x16x32_bf16(xv1, bx0b, a0b, 0, 0, 0);
    a1b = __builtin_amdgcn_mfma_f32_16x16x32_bf16(xv1, bx1b, a1b, 0, 0, 0);
    if (t > 0) {
#pragma unroll
      for (int s = 0; s < 16; ++s) {
        bf16x8 av;
        *(unsigned long long*)&av = u0[s];
        *((unsigned long long*)&av + 1) = u1[s];
        int cs = (((4 * s + ko) ^ mx) << 3);
        bf16x8 bv0 = *(const bf16x8*)&Wl[r0 * 576 + cs];
        bf16x8 bv1 = *(const bf16x8*)&Wl[(r0 + 16) * 576 + cs];
        if (s & 1) {
          a0b = __builtin_amdgcn_mfma_f32_16x16x32_bf16(av, bv0, a0b, 0, 0, 0);
          a1b = __builtin_amdgcn_mfma_f32_16x16x32_bf16(av, bv1, a1b, 0, 0, 0);
        } else {
          a0a = __builtin_amdgcn_mfma_f32_16x16x32_bf16(av, bv0, a0a, 0, 0, 0);
          a1a = __builtin_amdgcn_mfma_f32_16x16x32_bf16(av, bv1, a1a, 0, 0, 0);
        }
      }
    }
    f32x4 A0 = a0a + a0b;
    f32x4 A1 = a1a + a1b;

    // ---- epilogue: quad gather (rot d brings lane(q+d)'s A[q]) ----
    // D layout: col = lane&15 -> (q,jj); row = 4ko+reg -> batch. Lane q owns
    // reg q: cell (batch 4ko+q, col j). send_d = A[(q-d)&3].
    float own0 = q0 ? A0.x : q1 ? A0.y : q2 ? A0.z : A0.w;
    float t1s0 = q0 ? A0.w : q1 ? A0.x : q2 ? A0.y : A0.z;
    float t2s0 = q0 ? A0.z : q1 ? A0.w : q2 ? A0.x : A0.y;
    float t3s0 = q0 ? A0.y : q1 ? A0.z : q2 ? A0.w : A0.x;
    float r1_0 = dppq<0x39>(t1s0);  // quad rot +1
    float r2_0 = dppq<0x4E>(t2s0);  // quad rot +2
    float r3_0 = dppq<0x93>(t3s0);  // quad rot +3
    float own1 = q0 ? A1.x : q1 ? A1.y : q2 ? A1.z : A1.w;
    float t1s1 = q0 ? A1.w : q1 ? A1.x : q2 ? A1.y : A1.z;
    float t2s1 = q0 ? A1.z : q1 ? A1.w : q2 ? A1.x : A1.y;
    float t3s1 = q0 ? A1.y : q1 ? A1.z : q2 ? A1.w : A1.x;
    float r1_1 = dppq<0x39>(t1s1);
    float r2_1 = dppq<0x4E>(t2s1);
    float r3_1 = dppq<0x93>(t3s1);
    // gate g' = s_{(g'-q)&3}, s_0=own, s_d=r_d
    float gi0 = (q0 ? own0 : q1 ? r3_0 : q2 ? r2_0 : r1_0) + bi0[0];
    float gf0 = (q0 ? r1_0 : q1 ? own0 : q2 ? r3_0 : r2_0) + bi0[1];
    float gg0 = (q0 ? r2_0 : q1 ? r1_0 : q2 ? own0 : r3_0) + bi0[2];
    float go0 = (q0 ? r3_0 : q1 ? r2_0 : q2 ? r1_0 : own0) + bi0[3];
    float gi1 = (q0 ? own1 : q1 ? r3_1 : q2 ? r2_1 : r1_1) + bi1[0];
    float gf1 = (q0 ? r1_1 : q1 ? own1 : q2 ? r3_1 : r2_1) + bi1[1];
    float gg1 = (q0 ? r2_1 : q1 ? r1_1 : q2 ? own1 : r3_1) + bi1[2];
    float go1 = (q0 ? r3_1 : q1 ? r2_1 : q2 ? r1_1 : own1) + bi1[3];

    float ii0 = rcpf(1.f + __expf(-gi0));
    float ff0 = rcpf(1.f + __expf(-gf0));
    float tg0 = 2.f * rcpf(1.f + __expf(-2.f * gg0)) - 1.f;
    float oo0 = rcpf(1.f + __expf(-go0));
    cc0 = ff0 * cc0 + ii0 * tg0;
    float h0 = oo0 * (2.f * rcpf(1.f + __expf(-2.f * cc0)) - 1.f);

    float ii1 = rcpf(1.f + __expf(-gi1));
    float ff1 = rcpf(1.f + __expf(-gf1));
    float tg1 = 2.f * rcpf(1.f + __expf(-2.f * gg1)) - 1.f;
    float oo1 = rcpf(1.f + __expf(-go1));
    cc1 = ff1 * cc1 + ii1 * tg1;
    float h1 = oo1 * (2.f * rcpf(1.f + __expf(-2.f * cc1)) - 1.f);

    // pack col pairs (jj even takes partner jj+1 via xor-4) and publish
    float h0p = __shfl_xor(h0, 4);
    float h1p = __shfl_xor(h1, 4);
    if (!(jj & 1)) {
      unsigned p0 = (unsigned)f2bf(h0) | ((unsigned)f2bf(h0p) << 16);
      unsigned p1 = (unsigned)f2bf(h1) | ((unsigned)f2bf(h1p) << 16);
      unsigned* d = (unsigned*)(hs + ((size_t)t * BT + bbase + 4 * ko + q) * HH +
                                n * 32 + 8 * w + jj);
      __hip_atomic_store(d, p0, __ATOMIC_RELAXED, __HIP_MEMORY_SCOPE_AGENT);
      __hip_atomic_store(d + 2, p1, __ATOMIC_RELAXED, __HIP_MEMORY_SCOPE_AGENT);
    }
  }
}

// Ax[t][b][k] = bf16(points[t][b][k]) for k<34 else 0
__global__ void __launch_bounds__(256) prep_ax(const float* __restrict__ pts,
                                               unsigned short* __restrict__ Ax) {
  size_t i = (size_t)blockIdx.x * 256 + threadIdx.x;  // [0, 512*256*64)
  int k = (int)(i & 63);
  size_t tb = i >> 6;
  float v = (k < NP) ? pts[tb * NP + k] : 0.f;
  Ax[i] = f2bf(v);
}

// logits = hs @ W_lin^T + b_lin ; softmax over 16
__global__ void __launch_bounds__(256) head_kernel(const unsigned short* __restrict__ hs,
                                                   const float* __restrict__ Wlin,
                                                   const float* __restrict__ blin,
                                                   float* __restrict__ out) {
  __shared__ float wl[16 * 513];
  __shared__ float bl[16];
  __shared__ unsigned short hl[16 * 520];
  const int tid = threadIdx.x;
  for (int i = tid; i < 16 * 512; i += 256) wl[(i >> 9) * 513 + (i & 511)] = Wlin[i];
  if (tid < 16) bl[tid] = blin[tid];
  const size_t Rb = (size_t)blockIdx.x * 16;  // 16 rows of [131072][512]
  const uint4* gsrc = (const uint4*)(hs + Rb * 512);
#pragma unroll
  for (int j = 0; j < 4; ++j) {
    int e8 = tid + 256 * j;  // uint4 index, 8 bf16 each
    uint4 v = gsrc[e8];
    int r = e8 >> 6, k = (e8 & 63) << 3;
    *(uint4*)&hl[r * 520 + k] = v;
  }
  __syncthreads();
  const int r = tid >> 4, tg = tid & 15;
  float acc = bl[tg];
  const float* wp = &wl[tg * 513];
#pragma unroll 4
  for (int k8 = 0; k8 < 64; ++k8) {
    uint4 hv = *(const uint4*)&hl[r * 520 + (k8 << 3)];
    const float* w8 = wp + (k8 << 3);
    acc += __uint_as_float(hv.x << 16) * w8[0];
    acc += __uint_as_float(hv.x & 0xffff0000u) * w8[1];
    acc += __uint_as_float(hv.y << 16) * w8[2];
    acc += __uint_as_float(hv.y & 0xffff0000u) * w8[3];
    acc += __uint_as_float(hv.z << 16) * w8[4];
    acc += __uint_as_float(hv.z & 0xffff0000u) * w8[5];
    acc += __uint_as_float(hv.w << 16) * w8[6];
    acc += __uint_as_float(hv.w & 0xffff0000u) * w8[7];
  }
  float mx = acc;
#pragma unroll
  for (int d = 8; d; d >>= 1) mx = fmaxf(mx, __shfl_xor(mx, d, 16));
  float e = __expf(acc - mx);
  float sm = e;
#pragma unroll
  for (int d = 8; d; d >>= 1) sm += __shfl_xor(sm, d, 16);
  out[Rb * 16 + tid] = e / sm;
}

extern "C" void kernel_launch(void* const* d_in, const int* in_sizes, int n_in,
                              void* d_out, int out_size, void* d_ws, size_t ws_size,
                              hipStream_t stream) {
  (void)in_sizes; (void)n_in; (void)out_size; (void)ws_size;
  const float* pts  = (const float*)d_in[0];
  const float* Wih  = (const float*)d_in[1];
  const float* Whh  = (const float*)d_in[2];
  const float* bih  = (const float*)d_in[3];
  const float* bhh  = (const float*)d_in[4];
  const float* Wlin = (const float*)d_in[5];
  const float* blin = (const float*)d_in[6];
  float* out = (float*)d_out;
  char* ws = (char*)d_ws;
  // ws layout: hs 134217728 B | Ax 16777216 B
  unsigned short* hs = (unsigned short*)ws;
  unsigned short* Ax = (unsigned short*)(ws + 134217728);

  // sentinel-fill hs (self-validating exchange protocol needs every launch)
  hipMemsetAsync(hs, 0xAA, 134217728, stream);
  prep_ax<<<32768, 256, 0, stream>>>(pts, Ax);
  (void)hipFuncSetAttribute((const void*)lstm_coop,
                            hipFuncAttributeMaxDynamicSharedMemorySize, 147456);
  void* args[6];
  args[0] = (void*)&Whh; args[1] = (void*)&Wih; args[2] = (void*)&bih;
  args[3] = (void*)&bhh; args[4] = (void*)&Ax;  args[5] = (void*)&hs;
  hipLaunchCooperativeKernel((void*)lstm_coop, dim3(256), dim3(256), args, 147456, stream);
  head_kernel<<<8192, 256, 0, stream>>>(hs, Wlin, blin, out);
}

// Round 2
// 2449.737 us; speedup vs baseline: 3.8260x; 3.8260x over previous
//
#include <hip/hip_runtime.h>

// LSTM T=512 B=256 NP=34 H=512 NT=16.
// 16 groups (16 batches) x 16 blocks (32 h-cols, all 4 gates).
// R5 = R3's proven block-cooperative coalesced poll + LDS h-staging
//      + R4's in-register DPP epilogue (no gates LDS, no B2/B3/B4)
//      + double-buffered h-stage -> exactly ONE __syncthreads per step
//      + x W-fragments hoisted to registers (W LDS slice is Whh only)
//      + 4 MFMA accumulator chains; x-MFMAs issued before the poll.
// Sync scheme unchanged: hs pre-memset to sentinel; every h dword written
// once by a relaxed agent-scope store; consumers poll the exact dwords they
// need until != sentinel (successful poll IS the data load).
#define TT 512
#define BT 256
#define NP 34
#define HH 512
#define SENT 0xAAAAAAAAu

typedef short bf16x8 __attribute__((ext_vector_type(8)));
typedef float f32x4 __attribute__((ext_vector_type(4)));

static __device__ __forceinline__ unsigned short f2bf(float x) {
  unsigned int u = __float_as_uint(x);
  return (unsigned short)((u + 0x7fffu + ((u >> 16) & 1u)) >> 16);
}

template <int CTRL>
static __device__ __forceinline__ float dppq(float x) {
  return __int_as_float(
      __builtin_amdgcn_mov_dpp(__float_as_int(x), CTRL, 0xF, 0xF, true));
}

static __device__ __forceinline__ float rcpf(float x) {
  return __builtin_amdgcn_rcpf(x);
}

// LDS (163840 B dynamic):
//   [0, 131072)        Whh slice bf16 [128 rows][512], 16B-chunk swizzle
//                      phys_chunk = c ^ (r&7). Row r = j*4 + q (j=col, q=gate).
//   [131072, 163840)   h-stage bf16 2 x [16][512] (same swizzle), double-buffered.
__global__ void __launch_bounds__(256, 1) lstm_coop(
    const float* __restrict__ Whh, const float* __restrict__ Wih,
    const float* __restrict__ bih, const float* __restrict__ bhh,
    const unsigned short* __restrict__ Ax,  // [T][256][64] bf16: [points(34),0..]
    unsigned short* hs)                     // [T][256][512] bf16, pre-set SENT
{
  extern __shared__ char smem[];
  unsigned short* Wl = (unsigned short*)smem;
  unsigned short* stg = (unsigned short*)(smem + 131072);

  const int tid = threadIdx.x;
  const int g = blockIdx.x & 15;   // group
  const int n = blockIdx.x >> 4;   // h-col slice [n*32, n*32+32)
  const int bbase = g * 16;

  // ---- init resident Whh slice (swizzled, reordered rows r = j*4+q) ----
  for (int idx = tid; idx < 128 * 512; idx += 256) {
    int r = idx >> 9, k = idx & 511;
    int grow = (r & 3) * 512 + n * 32 + (r >> 2);
    float v = Whh[(size_t)grow * 512 + k];
    int c = k >> 3;
    Wl[r * 512 + ((c ^ (r & 7)) << 3) + (k & 7)] = f2bf(v);
  }

  const int lane = tid & 63;
  const int w = tid >> 6;        // wave: owns cols [8w, 8w+8) of this slice
  const int m = lane & 15;       // A row (batch) / B tile-row
  const int ko = lane >> 4;      // k-subgroup
  const int r0 = 32 * w + m;
  const int q = m & 3;           // gate owned by this lane
  const int jj = m >> 2;         // col-in-wave quad group
  const int j0 = 8 * w + jj;     // acc0 col (block-local)
  const int j1 = j0 + 4;         // acc1 col
  const int mx = m & 7;

  // biases for all 4 gates at cols j0, j1
  float bi0[4], bi1[4];
#pragma unroll
  for (int gg = 0; gg < 4; ++gg) {
    int gr0 = gg * 512 + n * 32 + j0;
    int gr1 = gg * 512 + n * 32 + j1;
    bi0[gg] = bih[gr0] + bhh[gr0];
    bi1[gg] = bih[gr1] + bhh[gr1];
  }

  // hoisted x-slice W fragments (constant over t), straight from global Wih
  bf16x8 bx0a, bx1a, bx0b, bx1b;
  {
    int grow0 = q * 512 + n * 32 + j0;  // row r0   -> (gate q, col j0)
    int grow1 = q * 512 + n * 32 + j1;  // row r0+16 -> (gate q, col j1)
#pragma unroll
    for (int e = 0; e < 8; ++e) {
      int ka = 8 * ko + e;        // [0,32) always < 34
      int kb = 32 + 8 * ko + e;   // valid only while < 34
      bx0a[e] = (short)f2bf(Wih[grow0 * 34 + ka]);
      bx1a[e] = (short)f2bf(Wih[grow1 * 34 + ka]);
      bx0b[e] = (kb < NP) ? (short)f2bf(Wih[grow0 * 34 + kb]) : (short)0;
      bx1b[e] = (kb < NP) ? (short)f2bf(Wih[grow1 * 34 + kb]) : (short)0;
    }
  }
  __syncthreads();  // Wl ready (read-only hereafter)

  const bool q0 = (q == 0), q1 = (q == 1), q2 = (q == 2);
  float cc0 = 0.f, cc1 = 0.f;  // cell state for (batch 4ko+q, cols j0/j1)

  for (int t = 0; t < TT; ++t) {
    // x fragments for this step (independent of h)
    const unsigned short* xbase = Ax + ((size_t)t * BT + bbase + m) * 64;
    bf16x8 xv0 = *(const bf16x8*)(xbase + (ko << 3));
    bf16x8 xv1 = *(const bf16x8*)(xbase + 32 + (ko << 3));

    // x MFMAs start the 4 accumulator chains; they run under the poll wait
    f32x4 a0a = {0.f, 0.f, 0.f, 0.f}, a0b = {0.f, 0.f, 0.f, 0.f};
    f32x4 a1a = {0.f, 0.f, 0.f, 0.f}, a1b = {0.f, 0.f, 0.f, 0.f};
    a0a = __builtin_amdgcn_mfma_f32_16x16x32_bf16(xv0, bx0a, a0a, 0, 0, 0);
    a1a = __builtin_amdgcn_mfma_f32_16x16x32_bf16(xv0, bx1a, a1a, 0, 0, 0);
    a0b = __builtin_amdgcn_mfma_f32_16x16x32_bf16(xv1, bx0b, a0b, 0, 0, 0);
    a1b = __builtin_amdgcn_mfma_f32_16x16x32_bf16(xv1, bx1b, a1b, 0, 0, 0);

    // ---- acquire h(t-1): cooperative coalesced poll, 8 u64/thread ----
    unsigned long long hv[8];
    if (t > 0) {
      const unsigned long long* hb =
          (const unsigned long long*)(hs + ((size_t)(t - 1) * BT + bbase) * HH);
      unsigned int vm = 0;
      int guard = 0;
      while (vm != 0xffu) {
#pragma unroll
        for (int u = 0; u < 8; ++u) {
          if (!((vm >> u) & 1u)) {
            unsigned long long x = __hip_atomic_load(hb + u * 256 + tid,
                                                     __ATOMIC_RELAXED,
                                                     __HIP_MEMORY_SCOPE_AGENT);
            if ((unsigned)x != SENT && (unsigned)(x >> 32) != SENT) {
              hv[u] = x;
              vm |= (1u << u);
            }
          }
        }
        if (vm == 0xffu) break;
        if (++guard > (1 << 20)) break;  // deadlock guard
        __builtin_amdgcn_s_sleep(1);
      }
    } else {
#pragma unroll
      for (int u = 0; u < 8; ++u) hv[u] = 0ull;
    }
    // stage into LDS (swizzled), double-buffered by t parity
    unsigned short* st = stg + (t & 1) * 8192;
#pragma unroll
    for (int u = 0; u < 8; ++u) {
      int idx = u * 256 + tid;           // [0,2048) 8B units
      int mm = idx >> 7, cu = idx & 127; // row, 8B unit in row
      int c16 = cu >> 1, half = cu & 1;
      *(unsigned long long*)&st[mm * 512 + ((c16 ^ (mm & 7)) << 3) + (half << 2)] = hv[u];
    }
    __syncthreads();  // the only per-step barrier: stage visible

    // ---- gates GEMM over h, 4 accumulator chains ----
#pragma unroll
    for (int s = 0; s < 16; ++s) {
      int cs = (((4 * s + ko) ^ mx) << 3);
      bf16x8 av = *(const bf16x8*)&st[m * 512 + cs];
      bf16x8 bv0 = *(const bf16x8*)&Wl[r0 * 512 + cs];
      bf16x8 bv1 = *(const bf16x8*)&Wl[(r0 + 16) * 512 + cs];
      if (s & 1) {
        a0b = __builtin_amdgcn_mfma_f32_16x16x32_bf16(av, bv0, a0b, 0, 0, 0);
        a1b = __builtin_amdgcn_mfma_f32_16x16x32_bf16(av, bv1, a1b, 0, 0, 0);
      } else {
        a0a = __builtin_amdgcn_mfma_f32_16x16x32_bf16(av, bv0, a0a, 0, 0, 0);
        a1a = __builtin_amdgcn_mfma_f32_16x16x32_bf16(av, bv1, a1a, 0, 0, 0);
      }
    }
    f32x4 A0 = a0a + a0b;
    f32x4 A1 = a1a + a1b;

    // ---- epilogue: quad gather (rot d brings lane(q+d)'s A[q]) ----
    // D layout: col = lane&15 -> (q,jj); row = 4ko+reg -> batch. Lane q owns
    // reg q: cell (batch 4ko+q, col j). send_d = A[(q-d)&3].
    float own0 = q0 ? A0.x : q1 ? A0.y : q2 ? A0.z : A0.w;
    float t1s0 = q0 ? A0.w : q1 ? A0.x : q2 ? A0.y : A0.z;
    float t2s0 = q0 ? A0.z : q1 ? A0.w : q2 ? A0.x : A0.y;
    float t3s0 = q0 ? A0.y : q1 ? A0.z : q2 ? A0.w : A0.x;
    float r1_0 = dppq<0x39>(t1s0);  // quad rot +1
    float r2_0 = dppq<0x4E>(t2s0);  // quad rot +2
    float r3_0 = dppq<0x93>(t3s0);  // quad rot +3
    float own1 = q0 ? A1.x : q1 ? A1.y : q2 ? A1.z : A1.w;
    float t1s1 = q0 ? A1.w : q1 ? A1.x : q2 ? A1.y : A1.z;
    float t2s1 = q0 ? A1.z : q1 ? A1.w : q2 ? A1.x : A1.y;
    float t3s1 = q0 ? A1.y : q1 ? A1.z : q2 ? A1.w : A1.x;
    float r1_1 = dppq<0x39>(t1s1);
    float r2_1 = dppq<0x4E>(t2s1);
    float r3_1 = dppq<0x93>(t3s1);
    // gate g' = s_{(g'-q)&3}, s_0=own, s_d=r_d
    float gi0 = (q0 ? own0 : q1 ? r3_0 : q2 ? r2_0 : r1_0) + bi0[0];
    float gf0 = (q0 ? r1_0 : q1 ? own0 : q2 ? r3_0 : r2_0) + bi0[1];
    float gg0 = (q0 ? r2_0 : q1 ? r1_0 : q2 ? own0 : r3_0) + bi0[2];
    float go0 = (q0 ? r3_0 : q1 ? r2_0 : q2 ? r1_0 : own0) + bi0[3];
    float gi1 = (q0 ? own1 : q1 ? r3_1 : q2 ? r2_1 : r1_1) + bi1[0];
    float gf1 = (q0 ? r1_1 : q1 ? own1 : q2 ? r3_1 : r2_1) + bi1[1];
    float gg1 = (q0 ? r2_1 : q1 ? r1_1 : q2 ? own1 : r3_1) + bi1[2];
    float go1 = (q0 ? r3_1 : q1 ? r2_1 : q2 ? r1_1 : own1) + bi1[3];

    float ii0 = rcpf(1.f + __expf(-gi0));
    float ff0 = rcpf(1.f + __expf(-gf0));
    float tg0 = 2.f * rcpf(1.f + __expf(-2.f * gg0)) - 1.f;
    float oo0 = rcpf(1.f + __expf(-go0));
    cc0 = ff0 * cc0 + ii0 * tg0;
    float h0 = oo0 * (2.f * rcpf(1.f + __expf(-2.f * cc0)) - 1.f);

    float ii1 = rcpf(1.f + __expf(-gi1));
    float ff1 = rcpf(1.f + __expf(-gf1));
    float tg1 = 2.f * rcpf(1.f + __expf(-2.f * gg1)) - 1.f;
    float oo1 = rcpf(1.f + __expf(-go1));
    cc1 = ff1 * cc1 + ii1 * tg1;
    float h1 = oo1 * (2.f * rcpf(1.f + __expf(-2.f * cc1)) - 1.f);

    // pack col pairs (jj even takes partner jj+1 via xor-4) and publish
    float h0p = __shfl_xor(h0, 4);
    float h1p = __shfl_xor(h1, 4);
    if (!(jj & 1)) {
      unsigned p0 = (unsigned)f2bf(h0) | ((unsigned)f2bf(h0p) << 16);
      unsigned p1 = (unsigned)f2bf(h1) | ((unsigned)f2bf(h1p) << 16);
      unsigned* d = (unsigned*)(hs + ((size_t)t * BT + bbase + 4 * ko + q) * HH +
                                n * 32 + 8 * w + jj);
      __hip_atomic_store(d, p0, __ATOMIC_RELAXED, __HIP_MEMORY_SCOPE_AGENT);
      __hip_atomic_store(d + 2, p1, __ATOMIC_RELAXED, __HIP_MEMORY_SCOPE_AGENT);
    }
  }
}

// Ax[t][b][k] = bf16(points[t][b][k]) for k<34 else 0
__global__ void __launch_bounds__(256) prep_ax(const float* __restrict__ pts,
                                               unsigned short* __restrict__ Ax) {
  size_t i = (size_t)blockIdx.x * 256 + threadIdx.x;  // [0, 512*256*64)
  int k = (int)(i & 63);
  size_t tb = i >> 6;
  float v = (k < NP) ? pts[tb * NP + k] : 0.f;
  Ax[i] = f2bf(v);
}

// logits = hs @ W_lin^T + b_lin ; softmax over 16
__global__ void __launch_bounds__(256) head_kernel(const unsigned short* __restrict__ hs,
                                                   const float* __restrict__ Wlin,
                                                   const float* __restrict__ blin,
                                                   float* __restrict__ out) {
  __shared__ float wl[16 * 513];
  __shared__ float bl[16];
  __shared__ unsigned short hl[16 * 520];
  const int tid = threadIdx.x;
  for (int i = tid; i < 16 * 512; i += 256) wl[(i >> 9) * 513 + (i & 511)] = Wlin[i];
  if (tid < 16) bl[tid] = blin[tid];
  const size_t Rb = (size_t)blockIdx.x * 16;  // 16 rows of [131072][512]
  const uint4* gsrc = (const uint4*)(hs + Rb * 512);
#pragma unroll
  for (int j = 0; j < 4; ++j) {
    int e8 = tid + 256 * j;  // uint4 index, 8 bf16 each
    uint4 v = gsrc[e8];
    int r = e8 >> 6, k = (e8 & 63) << 3;
    *(uint4*)&hl[r * 520 + k] = v;
  }
  __syncthreads();
  const int r = tid >> 4, tg = tid & 15;
  float acc = bl[tg];
  const float* wp = &wl[tg * 513];
#pragma unroll 4
  for (int k8 = 0; k8 < 64; ++k8) {
    uint4 hv = *(const uint4*)&hl[r * 520 + (k8 << 3)];
    const float* w8 = wp + (k8 << 3);
    acc += __uint_as_float(hv.x << 16) * w8[0];
    acc += __uint_as_float(hv.x & 0xffff0000u) * w8[1];
    acc += __uint_as_float(hv.y << 16) * w8[2];
    acc += __uint_as_float(hv.y & 0xffff0000u) * w8[3];
    acc += __uint_as_float(hv.z << 16) * w8[4];
    acc += __uint_as_float(hv.z & 0xffff0000u) * w8[5];
    acc += __uint_as_float(hv.w << 16) * w8[6];
    acc += __uint_as_float(hv.w & 0xffff0000u) * w8[7];
  }
  float mx = acc;
#pragma unroll
  for (int d = 8; d; d >>= 1) mx = fmaxf(mx, __shfl_xor(mx, d, 16));
  float e = __expf(acc - mx);
  float sm = e;
#pragma unroll
  for (int d = 8; d; d >>= 1) sm += __shfl_xor(sm, d, 16);
  out[Rb * 16 + tid] = e / sm;
}

extern "C" void kernel_launch(void* const* d_in, const int* in_sizes, int n_in,
                              void* d_out, int out_size, void* d_ws, size_t ws_size,
                              hipStream_t stream) {
  (void)in_sizes; (void)n_in; (void)out_size; (void)ws_size;
  const float* pts  = (const float*)d_in[0];
  const float* Wih  = (const float*)d_in[1];
  const float* Whh  = (const float*)d_in[2];
  const float* bih  = (const float*)d_in[3];
  const float* bhh  = (const float*)d_in[4];
  const float* Wlin = (const float*)d_in[5];
  const float* blin = (const float*)d_in[6];
  float* out = (float*)d_out;
  char* ws = (char*)d_ws;
  // ws layout: hs 134217728 B | Ax 16777216 B
  unsigned short* hs = (unsigned short*)ws;
  unsigned short* Ax = (unsigned short*)(ws + 134217728);

  // sentinel-fill hs (self-validating exchange protocol needs every launch)
  hipMemsetAsync(hs, 0xAA, 134217728, stream);
  prep_ax<<<32768, 256, 0, stream>>>(pts, Ax);
  (void)hipFuncSetAttribute((const void*)lstm_coop,
                            hipFuncAttributeMaxDynamicSharedMemorySize, 163840);
  void* args[6];
  args[0] = (void*)&Whh; args[1] = (void*)&Wih; args[2] = (void*)&bih;
  args[3] = (void*)&bhh; args[4] = (void*)&Ax;  args[5] = (void*)&hs;
  hipLaunchCooperativeKernel((void*)lstm_coop, dim3(256), dim3(256), args, 163840, stream);
  head_kernel<<<8192, 256, 0, stream>>>(hs, Wlin, blin, out);
}